// Round 5
// baseline (411.646 us; speedup 1.0000x reference)
//
#include <hip/hip_runtime.h>

typedef _Float16 f16;
typedef __attribute__((ext_vector_type(8))) _Float16 f16x8;
typedef __attribute__((ext_vector_type(4))) _Float16 f16x4;
typedef __attribute__((ext_vector_type(4))) float    f32x4;

#define MFMA(a,b,c) __builtin_amdgcn_mfma_f32_16x16x32_f16(a,b,c,0,0,0)

// problem constants
constexpr int Bc = 2, Nc = 65536, Cc = 256, Hc = 8;
constexpr int CHUNK = 512;                 // tokens per block: 4 m0-tiles of 128
constexpr int LDX = 72;                    // fallback staging stride (16B-aligned rows!)
constexpr int LDT = 136;                   // fallback transpose stride
// Rounds 2/3 lesson: LDS strides whose rows break 16B alignment of ds_*_b128
// (LDX=68 -> 136B rows) cost 201->473 µs with zero bank conflicts. Alignment
// is non-negotiable; conflicts are the cheap problem.

// ---- workspace layout (bytes) ----
// 0      : Tg    float[16*4096] (262144)
// 262144 : normg float[16*64]   (4096)
// 266240 : WC    f16[8*128*256] (524288)  [h][n][k]; n 0..63 = Wfx cols, 64..127 = Wxs
// 790528 : bsp   float[8*64]    (2048)
// 1048576: x16   f16[131072*256] (67108864)  [big-ws path only]
constexpr size_t X16_OFF = 1048576;
constexpr size_t WS_BIG  = X16_OFF + (size_t)131072 * 256 * 2;

__device__ __forceinline__ f32x4 splat4(float v) { f32x4 r; r.x=v; r.y=v; r.z=v; r.w=v; return r; }
__device__ __forceinline__ f16x8 pack8(float4 a, float4 b) {
  f16x8 r = { (f16)a.x,(f16)a.y,(f16)a.z,(f16)a.w,(f16)b.x,(f16)b.y,(f16)b.z,(f16)b.w };
  return r;
}

// async global->LDS, 16B/lane. Dest is wave-uniform base + lane*16 (m104).
__device__ __forceinline__ void gl_lds16(const f16* g, f16* l) {
  __builtin_amdgcn_global_load_lds((const __attribute__((address_space(1))) void*)g,
                                   (__attribute__((address_space(3))) void*)l, 16, 0, 0);
}
// barrier draining only LDS ops; memory clobber + sched_barrier pin LDS
// loads/stores on the correct side (rule #18 class).
__device__ __forceinline__ void bar_lgkm() {
  asm volatile("s_waitcnt lgkmcnt(0)" ::: "memory");
  __builtin_amdgcn_s_barrier();
  __builtin_amdgcn_sched_barrier(0);
}
// counted-vmcnt barrier: N loads may stay in flight (T4 — never drain to 0
// in the main loop).
template<int N> __device__ __forceinline__ void bar_vm() {
  __builtin_amdgcn_sched_barrier(0);
  asm volatile("s_waitcnt vmcnt(%0)" :: "i"(N) : "memory");
  __builtin_amdgcn_s_barrier();
  __builtin_amdgcn_sched_barrier(0);
}

// prep: cvt_blocks blocks convert x->f16 (8 elems/thread), then 97 prep
// blocks, then 65 blocks zero Tg+normg. Small-ws path launches with
// cvt_blocks=0.
__global__ void prep_b(const float* __restrict__ x, const float* __restrict__ Wx,
                       const float* __restrict__ Wfx, const float* __restrict__ Wsl,
                       const float* __restrict__ bx, const float* __restrict__ bsl,
                       f16* __restrict__ WC, float* __restrict__ bsp,
                       float* __restrict__ Tz, f16* __restrict__ x16, int cvt_blocks) {
  __shared__ float tile[64][72];
  int b = blockIdx.x;
  const int t = threadIdx.x;
  if (b < cvt_blocks) {                    // x -> f16 (same rounding as pack8)
    const long i = ((long)b * 256 + t) * 8;
    float4 a = *(const float4*)&x[i];
    float4 c = *(const float4*)&x[i + 4];
    *(f16x8*)&x16[i] = pack8(a, c);
    return;
  }
  b -= cvt_blocks;
  if (b < 32) {                            // transpose Wfx tile (k0..+64) x (c0..+64)
    const int k0 = (b & 3) * 64, c0 = (b >> 2) * 64;
    const int r = t >> 4, c4 = (t & 15) * 4;
    #pragma unroll
    for (int i = 0; i < 4; ++i) {
      float4 v = *(const float4*)&Wfx[(size_t)(k0 + r + i*16)*512 + c0 + c4];
      tile[r + i*16][c4] = v.x; tile[r + i*16][c4+1] = v.y;
      tile[r + i*16][c4+2] = v.z; tile[r + i*16][c4+3] = v.w;
    }
    __syncthreads();
    const int cl = t >> 2, kq = t & 3;
    const int col = c0 + cl, h = col >> 6, n = col & 63;
    f16 tmp[16];
    #pragma unroll
    for (int jj = 0; jj < 16; ++jj) tmp[jj] = (f16)tile[kq*16 + jj][cl];
    f16* dst = WC + (size_t)(h*128 + n)*256 + k0 + kq*16;
    *(f16x8*)dst       = *(f16x8*)&tmp[0];
    *(f16x8*)(dst + 8) = *(f16x8*)&tmp[8];
  } else if (b < 96) {                     // Wxs rows
    const int bb = b - 32;
    const int h = bb >> 3, k0 = (bb & 7) * 32;
    const int k = t & 31, sq = t >> 5;
    float accs[8];
    #pragma unroll
    for (int jj = 0; jj < 8; ++jj) accs[jj] = 0.f;
    for (int d = 0; d < 64; ++d) {
      float a = Wx[(size_t)(k0 + k)*512 + h*64 + d];
      #pragma unroll
      for (int jj = 0; jj < 8; ++jj) accs[jj] += a * Wsl[d*64 + sq*8 + jj];
    }
    #pragma unroll
    for (int jj = 0; jj < 8; ++jj)
      WC[(size_t)(h*128 + 64 + sq*8 + jj)*256 + k0 + k] = (f16)accs[jj];
  } else if (b == 96) {                    // bsp[h][s]
    for (int u = t; u < 512; u += 256) {
      int h = u >> 6, s = u & 63;
      float a = bsl[s];
      for (int d = 0; d < 64; ++d) a += bx[h*64 + d] * Wsl[d*64 + s];
      bsp[h*64 + s] = a;
    }
  } else {                                 // zero Tg + normg
    float4 z; z.x = z.y = z.z = z.w = 0.f;
    ((float4*)Tz)[(b - 97) * 256 + t] = z;
  }
}

// DMA-staged fused kernel. Round-4's null result (barrier overhaul -> 0 delta)
// showed the kernel is DS+VALU throughput-bound, not latency-bound. Here:
// - staging is global_load_lds width-16: no ds_writes, no xr/wr regs, no pack
//   VALU in the main loop (the f32->f16 conversion moved to prep_b, done 1x
//   instead of 8x per head).
// - LDS tiles are linear [128][64] (DMA requires it) with the rule-#21
//   both-sides XOR swizzle: inverse-swizzled GLOBAL source (slot^=(row&7) via
//   per-lane address) + swizzled ds_read. Fragment reads are uniform
//   8 words/bank (the b128 minimum). Transpose buffers [64][128] use the same
//   scheme at 16-slot granularity (col ^= (row&15)*8).
// - vmcnt(8) counted waits: the next tile's 8 DMA loads stay in flight across
//   the barrier and the current tile's MFMAs (T3/T4).
// LDS 64 KiB -> 2 blocks/CU. (256,1): body needs ~150 VGPR; a (256,2) 128-cap
// would spill (round-2 disaster).
__global__ __launch_bounds__(256, 1)
void fused_dma(const f16* __restrict__ x16, const float* __restrict__ bfx,
               const float* __restrict__ bsp, const float* __restrict__ temp,
               const f16* __restrict__ WC,   float* __restrict__ Tg,
               float* __restrict__ normg) {
  __shared__ alignas(1024) f16 smem[32768];          // 64 KiB
  f16* X0 = smem;          f16* W0 = smem +  8192;   // even tiles
  f16* X1 = smem + 16384;  f16* W1 = smem + 24576;   // odd tiles
  f16* sm_fxT = X1;                                  // alias: fx^T [64][128]
  f16* sm_wT  = W1;                                  // alias: w^T  [64][128]

  // XCD swizzle: all 8 heads of a chunk on one XCD (x16 chunk stays L2-hot)
  const int j    = blockIdx.x;
  const int xcd  = j & 7, slot = j >> 3;
  const int chunk = xcd * 32 + (slot >> 3);
  const int h     = slot & 7;

  const int tid = threadIdx.x;
  const int wv = tid >> 6, lane = tid & 63, quad = lane >> 4, ln = lane & 15;
  const int wm = wv >> 1, wn = wv & 1;
  const long tokBase = (long)chunk * CHUNK;
  const int b  = (int)(tokBase >> 16);
  const int bh = b * Hc + h;

  const float tc = fminf(fmaxf(temp[h], 0.5f), 5.0f);
  const float k2 = 1.44269504f / tc;

  float bv[4];
  {
    const float* bb = (wn == 0) ? (bfx + h*64) : (bsp + h*64);
    #pragma unroll
    for (int nt = 0; nt < 4; ++nt) bv[nt] = bb[nt*16 + ln];
  }

  f32x4 Tacc[2][2];
  #pragma unroll
  for (int i = 0; i < 2; ++i) { Tacc[i][0] = splat4(0.f); Tacc[i][1] = splat4(0.f); }
  float nacc[4] = {0.f, 0.f, 0.f, 0.f};
  const int ci = wv >> 1, cj = wv & 1;

  const f16* WCh = WC + (size_t)h * 128 * 256;

  // DMA source addressing: lane l writes LDS bytes (base + l*16); that slot is
  // physical slot (l&7) of row 8j+(l>>3). Physical slot p holds logical slot
  // p ^ (row&7), so the lane fetches global slot sl = (l&7) ^ (l>>3).
  const int l8 = lane >> 3;
  const int sl = (lane & 7) ^ l8;
  const f16* xg = x16 + (tokBase + wv*32 + l8) * 256 + sl*8;
  const f16* wg = WCh + (wv*32 + l8) * 256 + sl*8;

  auto stage = [&](int tt) {               // 8 DMA instrs/wave: 1/4 of X + W tile
    f16* bx_ = (tt & 1) ? X1 : X0;
    f16* bw_ = (tt & 1) ? W1 : W0;
    const f16* gx = xg + (long)(tt >> 2) * (128*256) + (tt & 3) * 64;
    const f16* gw = wg + (tt & 3) * 64;
    f16* lx = bx_ + wv * 2048;
    f16* lw = bw_ + wv * 2048;
    #pragma unroll
    for (int i = 0; i < 4; ++i) {
      gl_lds16(gx + i*2048, lx + i*512);
      gl_lds16(gw + i*2048, lw + i*512);
    }
  };

  const int swl = (ln & 7) * 8;            // staging-tile read swizzle (elems)
  const int swt = ln * 8;                  // transpose-buffer swizzle (elems)

  stage(0);                                // prologue: tile 0 in flight

  for (int m0 = 0; m0 < 4; ++m0) {
    // ---------- Phase A: [fx | sp] = x_tile(128x256) @ WC_h(256x128) ----------
    f32x4 acc[4][4];
    #pragma unroll
    for (int mt = 0; mt < 4; ++mt)
      #pragma unroll
      for (int nt = 0; nt < 4; ++nt) acc[mt][nt] = splat4(bv[nt]);

    #pragma unroll
    for (int kb = 0; kb < 4; ++kb) {
      const int t = m0*4 + kb;
      // WAR safe: buf[(t+1)&1] was last read at tile t-1, closed by that
      // iteration's bottom bar_lgkm.
      if (m0 == 3 && kb == 3) { bar_vm<0>(); }
      else                    { stage(t + 1); bar_vm<8>(); }   // tile t landed
      const f16* sx = (t & 1) ? X1 : X0;
      const f16* sw = (t & 1) ? W1 : W0;
      #pragma unroll
      for (int ks = 0; ks < 2; ++ks) {
        f16x8 af[4], bf[4];
        #pragma unroll
        for (int mt = 0; mt < 4; ++mt)
          af[mt] = *(const f16x8*)&sx[(wm*64 + mt*16 + ln)*64 + ((ks*32 + quad*8) ^ swl)];
        #pragma unroll
        for (int nt = 0; nt < 4; ++nt)
          bf[nt] = *(const f16x8*)&sw[(wn*64 + nt*16 + ln)*64 + ((ks*32 + quad*8) ^ swl)];
        #pragma unroll
        for (int mt = 0; mt < 4; ++mt)
          #pragma unroll
          for (int nt = 0; nt < 4; ++nt)
            acc[mt][nt] = MFMA(af[mt], bf[nt], acc[mt][nt]);
      }
      bar_lgkm();                          // all waves' reads of buf[t&1] retired
    }
    // here: kb3's bottom barrier closed all X1/W1 reads -> alias rewrite ok.
    // In-flight DMA (next m0's kb0 tile) targets X0/W0 only.

    // ---------- epilogue into aliased X1/W1 ----------
    if (wn == 0) {
      #pragma unroll
      for (int mt = 0; mt < 4; ++mt)
        #pragma unroll
        for (int nt = 0; nt < 4; ++nt) {
          f16x4 v = { (f16)acc[mt][nt][0], (f16)acc[mt][nt][1],
                      (f16)acc[mt][nt][2], (f16)acc[mt][nt][3] };
          *(f16x4*)&sm_fxT[(nt*16 + ln)*128 + ((wm*64 + mt*16 + quad*4) ^ swt)] = v;
        }
    } else {
      #pragma unroll
      for (int mt = 0; mt < 4; ++mt) {
        float e[4][4], wout[4][4];
        #pragma unroll
        for (int nt = 0; nt < 4; ++nt)
          #pragma unroll
          for (int rg = 0; rg < 4; ++rg)
            e[nt][rg] = exp2f(acc[mt][nt][rg] * k2);   // no max-sub: logits bounded
        #pragma unroll
        for (int rg = 0; rg < 4; ++rg) {
          float rs = e[0][rg] + e[1][rg] + e[2][rg] + e[3][rg];
          #pragma unroll
          for (int dd = 1; dd < 16; dd <<= 1) rs += __shfl_xor(rs, dd, 64);
          float inv = 1.0f / rs;
          #pragma unroll
          for (int nt = 0; nt < 4; ++nt) {
            wout[nt][rg] = e[nt][rg] * inv;
            nacc[nt] += wout[nt][rg];
          }
        }
        #pragma unroll
        for (int nt = 0; nt < 4; ++nt) {
          f16x4 v = { (f16)wout[nt][0], (f16)wout[nt][1],
                      (f16)wout[nt][2], (f16)wout[nt][3] };
          *(f16x4*)&sm_wT[(nt*16 + ln)*128 + ((wm*64 + mt*16 + quad*4) ^ swt)] = v;
        }
      }
    }
    bar_lgkm();                            // epilogue writes visible

    // ---------- Phase C: T[s][d] += w^T @ fx, K=128 ----------
    #pragma unroll
    for (int ks = 0; ks < 4; ++ks) {
      f16x8 a0 = *(const f16x8*)&sm_wT [(ci*32 +      ln)*128 + ((ks*32 + quad*8) ^ swt)];
      f16x8 a1 = *(const f16x8*)&sm_wT [(ci*32 + 16 + ln)*128 + ((ks*32 + quad*8) ^ swt)];
      f16x8 b0 = *(const f16x8*)&sm_fxT[(cj*32 +      ln)*128 + ((ks*32 + quad*8) ^ swt)];
      f16x8 b1 = *(const f16x8*)&sm_fxT[(cj*32 + 16 + ln)*128 + ((ks*32 + quad*8) ^ swt)];
      Tacc[0][0] = MFMA(a0, b0, Tacc[0][0]);
      Tacc[0][1] = MFMA(a0, b1, Tacc[0][1]);
      Tacc[1][0] = MFMA(a1, b0, Tacc[1][0]);
      Tacc[1][1] = MFMA(a1, b1, Tacc[1][1]);
    }
    bar_lgkm();                            // Phase-C reads retired before next m0
                                           // stages kb1's DMA into X1/W1
  }

  // ---------- flush ----------
  float* Tb = Tg + bh * 4096;
  #pragma unroll
  for (int mt2 = 0; mt2 < 2; ++mt2)
    #pragma unroll
    for (int nt2 = 0; nt2 < 2; ++nt2)
      #pragma unroll
      for (int rg = 0; rg < 4; ++rg) {
        int s = ci*32 + mt2*16 + quad*4 + rg;
        int d = cj*32 + nt2*16 + ln;
        atomicAdd(&Tb[s*64 + d], Tacc[mt2][nt2][rg]);
      }
  if (wn == 1) {
    #pragma unroll
    for (int nt = 0; nt < 4; ++nt) {
      float v = nacc[nt];
      v += __shfl_xor(v, 16, 64);
      v += __shfl_xor(v, 32, 64);
      if (lane < 16) atomicAdd(&normg[bh*64 + nt*16 + ln], v);
    }
  }
}

// Fallback (small workspace): round-4 kernel verbatim (201 µs measured).
__device__ __forceinline__ void wave_bar() {
  asm volatile("s_waitcnt lgkmcnt(0)" ::: "memory");
  __builtin_amdgcn_s_barrier();
  __builtin_amdgcn_sched_barrier(0);
}
__global__ __launch_bounds__(256, 2)
void fused_reg(const float* __restrict__ x,   const float* __restrict__ bfx,
               const float* __restrict__ bsp, const float* __restrict__ temp,
               const f16* __restrict__ WC,    float* __restrict__ Tg,
               float* __restrict__ normg) {
  __shared__ alignas(16) char smem[4 * 128 * LDX * 2];
  f16* X0 = (f16*)smem;
  f16* W0 = X0 + 128 * LDX;
  f16* X1 = W0 + 128 * LDX;
  f16* W1 = X1 + 128 * LDX;
  f16* sm_fxT = X1;
  f16* sm_wT  = W1;

  const int j    = blockIdx.x;
  const int xcd  = j & 7, slot = j >> 3;
  const int chunk = xcd * 32 + (slot >> 3);
  const int h     = slot & 7;

  const int tid = threadIdx.x;
  const int wv = tid >> 6, lane = tid & 63, quad = lane >> 4, ln = lane & 15;
  const int wm = wv >> 1, wn = wv & 1;
  const long tokBase = (long)chunk * CHUNK;
  const int b  = (int)(tokBase >> 16);
  const int bh = b * Hc + h;

  const float tc = fminf(fmaxf(temp[h], 0.5f), 5.0f);
  const float k2 = 1.44269504f / tc;

  float bv[4];
  {
    const float* bb = (wn == 0) ? (bfx + h*64) : (bsp + h*64);
    #pragma unroll
    for (int nt = 0; nt < 4; ++nt) bv[nt] = bb[nt*16 + ln];
  }

  f32x4 Tacc[2][2];
  #pragma unroll
  for (int i = 0; i < 2; ++i) { Tacc[i][0] = splat4(0.f); Tacc[i][1] = splat4(0.f); }
  float nacc[4] = {0.f, 0.f, 0.f, 0.f};
  const int ci = wv >> 1, cj = wv & 1;

  const f16* WCh = WC + (size_t)h * 128 * 256;
  const int r0 = tid >> 2, seg = tid & 3;
  const int wrow = tid >> 1, whalf = tid & 1;

  float4 xr[8]; f16x8 wr[4];
  auto loadx = [&](int m0, int kb) {
    const float* p = x + (tokBase + (long)m0*128 + r0)*Cc + kb*64 + seg*16;
    xr[0] = *(const float4*)p;        xr[1] = *(const float4*)(p + 4);
    xr[2] = *(const float4*)(p + 8);  xr[3] = *(const float4*)(p + 12);
    p += 64 * Cc;
    xr[4] = *(const float4*)p;        xr[5] = *(const float4*)(p + 4);
    xr[6] = *(const float4*)(p + 8);  xr[7] = *(const float4*)(p + 12);
  };
  auto loadw = [&](int kb) {
    const f16* p = WCh + wrow*256 + kb*64 + whalf*32;
    wr[0] = *(const f16x8*)p;         wr[1] = *(const f16x8*)(p + 8);
    wr[2] = *(const f16x8*)(p + 16);  wr[3] = *(const f16x8*)(p + 24);
  };

  loadx(0, 0); loadw(0);

  for (int m0 = 0; m0 < 4; ++m0) {
    f32x4 acc[4][4];
    #pragma unroll
    for (int mt = 0; mt < 4; ++mt)
      #pragma unroll
      for (int nt = 0; nt < 4; ++nt) acc[mt][nt] = splat4(bv[nt]);

    for (int kb = 0; kb < 4; ++kb) {
      const int t = m0*4 + kb;
      f16* sx = (t & 1) ? X1 : X0;
      f16* sw = (t & 1) ? W1 : W0;
      *(f16x8*)&sx[r0*LDX + seg*16]          = pack8(xr[0], xr[1]);
      *(f16x8*)&sx[r0*LDX + seg*16 + 8]      = pack8(xr[2], xr[3]);
      *(f16x8*)&sx[(r0+64)*LDX + seg*16]     = pack8(xr[4], xr[5]);
      *(f16x8*)&sx[(r0+64)*LDX + seg*16 + 8] = pack8(xr[6], xr[7]);
      *(f16x8*)&sw[wrow*LDX + whalf*32]      = wr[0];
      *(f16x8*)&sw[wrow*LDX + whalf*32 +  8] = wr[1];
      *(f16x8*)&sw[wrow*LDX + whalf*32 + 16] = wr[2];
      *(f16x8*)&sw[wrow*LDX + whalf*32 + 24] = wr[3];
      { int nt_ = t + 1;
        if (nt_ < 16) { loadx(nt_ >> 2, nt_ & 3); loadw(nt_ & 3); } }
      wave_bar();
      #pragma unroll
      for (int ks = 0; ks < 2; ++ks) {
        f16x8 af[4], bf[4];
        #pragma unroll
        for (int mt = 0; mt < 4; ++mt)
          af[mt] = *(const f16x8*)&sx[(wm*64 + mt*16 + ln)*LDX + ks*32 + quad*8];
        #pragma unroll
        for (int nt = 0; nt < 4; ++nt)
          bf[nt] = *(const f16x8*)&sw[(wn*64 + nt*16 + ln)*LDX + ks*32 + quad*8];
        #pragma unroll
        for (int mt = 0; mt < 4; ++mt)
          #pragma unroll
          for (int nt = 0; nt < 4; ++nt)
            acc[mt][nt] = MFMA(af[mt], bf[nt], acc[mt][nt]);
      }
    }
    wave_bar();

    if (wn == 0) {
      #pragma unroll
      for (int mt = 0; mt < 4; ++mt)
        #pragma unroll
        for (int nt = 0; nt < 4; ++nt) {
          f16x4 v = { (f16)acc[mt][nt][0], (f16)acc[mt][nt][1],
                      (f16)acc[mt][nt][2], (f16)acc[mt][nt][3] };
          *(f16x4*)&sm_fxT[(nt*16 + ln)*LDT + wm*64 + mt*16 + quad*4] = v;
        }
    } else {
      #pragma unroll
      for (int mt = 0; mt < 4; ++mt) {
        float e[4][4], wout[4][4];
        #pragma unroll
        for (int nt = 0; nt < 4; ++nt)
          #pragma unroll
          for (int rg = 0; rg < 4; ++rg)
            e[nt][rg] = exp2f(acc[mt][nt][rg] * k2);
        #pragma unroll
        for (int rg = 0; rg < 4; ++rg) {
          float rs = e[0][rg] + e[1][rg] + e[2][rg] + e[3][rg];
          #pragma unroll
          for (int dd = 1; dd < 16; dd <<= 1) rs += __shfl_xor(rs, dd, 64);
          float inv = 1.0f / rs;
          #pragma unroll
          for (int nt = 0; nt < 4; ++nt) {
            wout[nt][rg] = e[nt][rg] * inv;
            nacc[nt] += wout[nt][rg];
          }
        }
        #pragma unroll
        for (int nt = 0; nt < 4; ++nt) {
          f16x4 v = { (f16)wout[nt][0], (f16)wout[nt][1],
                      (f16)wout[nt][2], (f16)wout[nt][3] };
          *(f16x4*)&sm_wT[(nt*16 + ln)*LDT + wm*64 + mt*16 + quad*4] = v;
        }
      }
    }
    wave_bar();

    #pragma unroll
    for (int ks = 0; ks < 4; ++ks) {
      f16x8 a0 = *(const f16x8*)&sm_wT [(ci*32 +      ln)*LDT + ks*32 + quad*8];
      f16x8 a1 = *(const f16x8*)&sm_wT [(ci*32 + 16 + ln)*LDT + ks*32 + quad*8];
      f16x8 b0 = *(const f16x8*)&sm_fxT[(cj*32 +      ln)*LDT + ks*32 + quad*8];
      f16x8 b1 = *(const f16x8*)&sm_fxT[(cj*32 + 16 + ln)*LDT + ks*32 + quad*8];
      Tacc[0][0] = MFMA(a0, b0, Tacc[0][0]);
      Tacc[0][1] = MFMA(a0, b1, Tacc[0][1]);
      Tacc[1][0] = MFMA(a1, b0, Tacc[1][0]);
      Tacc[1][1] = MFMA(a1, b1, Tacc[1][1]);
    }
  }

  float* Tb = Tg + bh * 4096;
  #pragma unroll
  for (int mt2 = 0; mt2 < 2; ++mt2)
    #pragma unroll
    for (int nt2 = 0; nt2 < 2; ++nt2)
      #pragma unroll
      for (int rg = 0; rg < 4; ++rg) {
        int s = ci*32 + mt2*16 + quad*4 + rg;
        int d = cj*32 + nt2*16 + ln;
        atomicAdd(&Tb[s*64 + d], Tacc[mt2][nt2][rg]);
      }
  if (wn == 1) {
    #pragma unroll
    for (int nt = 0; nt < 4; ++nt) {
      float v = nacc[nt];
      v += __shfl_xor(v, 16, 64);
      v += __shfl_xor(v, 32, 64);
      if (lane < 16) atomicAdd(&normg[bh*64 + nt*16 + ln], v);
    }
  }
}

__global__ void finalize(const float* __restrict__ Tg, const float* __restrict__ normg,
                         float* __restrict__ out) {
  int i = blockIdx.x * 256 + threadIdx.x;
  out[i] = Tg[i] / (normg[i >> 6] + 0.01f);
}

extern "C" void kernel_launch(void* const* d_in, const int* in_sizes, int n_in,
                              void* d_out, int out_size, void* d_ws, size_t ws_size,
                              hipStream_t stream) {
  const float* x    = (const float*)d_in[0];
  const float* Wx   = (const float*)d_in[1];
  const float* bx   = (const float*)d_in[2];
  const float* Wfx  = (const float*)d_in[3];
  const float* bfx  = (const float*)d_in[4];
  const float* Wsl  = (const float*)d_in[5];
  const float* bsl  = (const float*)d_in[6];
  const float* temp = (const float*)d_in[7];
  float* out = (float*)d_out;

  float* Tg    = (float*)d_ws;
  float* normg = Tg + 16 * 4096;
  f16*   WC    = (f16*)((char*)d_ws + 266240);
  float* bsp   = (float*)((char*)d_ws + 790528);
  f16*   x16   = (f16*)((char*)d_ws + X16_OFF);

  if (ws_size >= WS_BIG) {
    prep_b   <<<16384 + 162, 256, 0, stream>>>(x, Wx, Wfx, Wsl, bx, bsl, WC, bsp, Tg, x16, 16384);
    fused_dma<<<2048, 256, 0, stream>>>(x16, bfx, bsp, temp, WC, Tg, normg);
  } else {
    prep_b   <<<162, 256, 0, stream>>>(x, Wx, Wfx, Wsl, bx, bsl, WC, bsp, Tg, x16, 0);
    fused_reg<<<2048, 256, 0, stream>>>(x, bfx, bsp, temp, WC, Tg, normg);
  }
  finalize <<<256, 256, 0, stream>>>(Tg, normg, out);
}